// Round 8
// baseline (176.284 us; speedup 1.0000x reference)
//
#include <hip/hip_runtime.h>

#define EPSBN 1e-5f

using s8v = __attribute__((ext_vector_type(8))) short;
using f4v = __attribute__((ext_vector_type(4))) float;

__device__ inline unsigned short f2bf(float f) {
  unsigned u = __float_as_uint(f);
  return (unsigned short)((u + 0x7FFFu + ((u >> 16) & 1u)) >> 16);
}

// ---------------- pack: concat(v,i) + NCHW f32 -> NHWC bf16 ----------------
__global__ __launch_bounds__(256) void k_pack(const float* __restrict__ v, const float* __restrict__ im,
                                              unsigned short* __restrict__ xb) {
  __shared__ float tile[64][33];
  int b = blockIdx.z;
  int hw0 = blockIdx.x * 32;
  int c0 = blockIdx.y * 64;
  int tx = threadIdx.x, ty = threadIdx.y;
#pragma unroll
  for (int i = 0; i < 64; i += 8) {
    int c = c0 + ty + i;
    const float* src = (c < 128) ? (v + ((size_t)b * 128 + c) * 4096)
                                 : (im + ((size_t)b * 128 + (c - 128)) * 4096);
    tile[ty + i][tx] = src[hw0 + tx];
  }
  __syncthreads();
#pragma unroll
  for (int i = 0; i < 32; i += 8) {
    int hw = hw0 + ty + i;
    ushort2 o;
    o.x = f2bf(tile[2 * tx][ty + i]);
    o.y = f2bf(tile[2 * tx + 1][ty + i]);
    *(ushort2*)&xb[((size_t)(b * 4096 + hw)) * 256 + c0 + 2 * tx] = o;
  }
}

// ---------------- merged weight prep: fragment-major bf16 (same verified mappings) ----------------
__global__ __launch_bounds__(256) void k_wprep_all(const float* __restrict__ w_off,
                                                   const float* __restrict__ w_d,
                                                   const float* __restrict__ w_2,
                                                   unsigned short* __restrict__ wt_off,
                                                   unsigned short* __restrict__ wt_d,
                                                   unsigned short* __restrict__ wt_2) {
  int bid = blockIdx.x, t = threadIdx.x;
  if (bid < 72) {  // offconv weights: 18432 frag-rows
    int id = bid * 256 + t;
    int lane = id & 63;
    int nb = (id >> 6) & 3;
    int ks = id >> 8;
    int ks2 = ks & 1, tap = (ks >> 1) % 9, cc = ks / 18;
    int o = nb * 16 + (lane & 15);
    int cb = cc * 64 + ks2 * 32 + ((lane >> 4) * 8);
    s8v r;
#pragma unroll
    for (int j = 0; j < 8; ++j) {
      float val = (o < 54) ? w_off[((size_t)o * 256 + cb + j) * 9 + tap] : 0.f;
      r[j] = (short)f2bf(val);
    }
    *(s8v*)&wt_off[(size_t)id * 8] = r;
  } else if (bid < 216) {  // dconv weights: 36864
    int id = (bid - 72) * 256 + t;
    int lane = id & 63;
    int nb = (id >> 6) & 7;
    int kstep = id >> 9;
    int chunk = kstep >> 2, ks4 = kstep & 3;
    int g = chunk / 9, kk = chunk % 9;
    int o = nb * 16 + (lane & 15);
    int cb = g * 128 + ks4 * 32 + ((lane >> 4) * 8);
    s8v r;
#pragma unroll
    for (int j = 0; j < 8; ++j) r[j] = (short)f2bf(w_d[((size_t)o * 256 + cb + j) * 9 + kk]);
    *(s8v*)&wt_d[(size_t)id * 8] = r;
  } else {  // conv2 weights: 18432
    int id = (bid - 216) * 256 + t;
    int lane = id & 63;
    int nb = (id >> 6) & 7;
    int kstep = id >> 9;
    int ks2 = kstep & 1, tap = (kstep >> 1) % 9, cc = kstep / 18;
    int o = nb * 16 + (lane & 15);
    int cb = cc * 64 + ks2 * 32 + ((lane >> 4) * 8);
    s8v r;
#pragma unroll
    for (int j = 0; j < 8; ++j) r[j] = (short)f2bf(w_2[((size_t)o * 128 + cb + j) * 9 + tap]);
    *(s8v*)&wt_2[(size_t)id * 8] = r;
  }
}

// ---------------- offset conv: waves = og(4) x kh(2), M=32, N=16/wave (unchanged) ----------------
__global__ __launch_bounds__(512, 3) void k_offconv(const unsigned short* __restrict__ xb,
                                                    const unsigned short* __restrict__ wt,
                                                    const float* __restrict__ bias,
                                                    float* __restrict__ off) {
  __shared__ char Xs[102 * 512];
  __shared__ float redx[2048];
  int bid = blockIdx.x;
  int id8 = (bid & 7) * 64 + (bid >> 3);
  int w0 = (id8 & 1) * 32;
  int h = (id8 >> 1) & 63;
  int b = id8 >> 7;
  int t = threadIdx.x;
  int l = t & 63, wv = t >> 6;
  int og = wv & 3, kh = wv >> 2;
  f4v zero = {0.f, 0.f, 0.f, 0.f};
  f4v acc[2] = {zero, zero};

  for (int id = t; id < 3264; id += 512) {
    int tr = id >> 5, oq8 = id & 31;
    int ky = tr / 34, col = tr % 34;
    int hh = h + ky - 1, ww = w0 + col - 1;
    s8v val = {0, 0, 0, 0, 0, 0, 0, 0};
    if ((unsigned)hh < 64u && (unsigned)ww < 64u)
      val = *(const s8v*)&xb[(((size_t)(b * 64 + hh)) * 64 + ww) * 256 + oq8 * 8];
    int byte = (tr * 512 + oq8 * 16) ^ ((tr & 7) << 4);
    *(s8v*)(Xs + byte) = val;
  }
  __syncthreads();
  int khi = l >> 4, lo = l & 15;
#pragma unroll
  for (int tap = 0; tap < 9; ++tap) {
    int ky = tap / 3, kx = tap % 3;
#pragma unroll
    for (int s = 0; s < 4; ++s) {
      int cc = kh * 2 + (s >> 1);
      int ks2 = s & 1;
      int kstep = cc * 18 + tap * 2 + ks2;
      int chb = cc * 128 + ks2 * 64 + khi * 16;
      s8v bfr = *(const s8v*)&wt[((size_t)(kstep * 4 + og) * 64 + l) * 8];
#pragma unroll
      for (int m = 0; m < 2; ++m) {
        int tr = ky * 34 + m * 16 + lo + kx;
        int rbyte = (tr * 512 + chb) ^ ((tr & 7) << 4);
        s8v a = *(const s8v*)(Xs + rbyte);
        acc[m] = __builtin_amdgcn_mfma_f32_16x16x32_bf16(a, bfr, acc[m], 0, 0, 0);
      }
    }
  }
  if (kh == 1) {
#pragma unroll
    for (int m = 0; m < 2; ++m)
#pragma unroll
      for (int j = 0; j < 4; ++j) redx[((og * 64 + l) * 2 + m) * 4 + j] = acc[m][j];
  }
  __syncthreads();
  if (kh == 0) {
    int o = og * 16 + lo;
    int pixb = (b * 64 + h) * 64 + w0;
    if (o < 54) {
      float bi = bias[o];
#pragma unroll
      for (int m = 0; m < 2; ++m)
#pragma unroll
        for (int j = 0; j < 4; ++j) {
          int px = pixb + m * 16 + khi * 4 + j;
          float vv = acc[m][j] + redx[((og * 64 + l) * 2 + m) * 4 + j] + bi;
          if (o >= 36) vv = 1.f / (1.f + __expf(-vv));
          off[(size_t)px * 54 + o] = vv;
        }
    }
  }
}

// ---------------- deform sample + dconv: M=64/block, 1 block/CU, raw-barrier dbuf ----------------
#define DC_ISSUE(c, V, Q)                                   \
  do {                                                      \
    const unsigned* ip_ = sidx[(c)][px];                    \
    const float* qp_ = swt[(c)][px];                        \
    Q##0 = qp_[0]; Q##1 = qp_[1]; Q##2 = qp_[2]; Q##3 = qp_[3]; \
    V##00 = *(const s8v*)&xb[ip_[0] + chof0];               \
    V##01 = *(const s8v*)&xb[ip_[1] + chof0];               \
    V##02 = *(const s8v*)&xb[ip_[2] + chof0];               \
    V##03 = *(const s8v*)&xb[ip_[3] + chof0];               \
    V##10 = *(const s8v*)&xb[ip_[0] + chof1];               \
    V##11 = *(const s8v*)&xb[ip_[1] + chof1];               \
    V##12 = *(const s8v*)&xb[ip_[2] + chof1];               \
    V##13 = *(const s8v*)&xb[ip_[3] + chof1];               \
  } while (0)

#define DC_HALF(c, A0, A1, A2, A3, Q, WB)                               \
  do {                                                                  \
    unsigned rr_[4];                                                    \
    _Pragma("unroll") for (int jp_ = 0; jp_ < 4; ++jp_) {               \
      unsigned w0_ = ((const unsigned*)&A0)[jp_];                       \
      unsigned w1_ = ((const unsigned*)&A1)[jp_];                       \
      unsigned w2_ = ((const unsigned*)&A2)[jp_];                       \
      unsigned w3_ = ((const unsigned*)&A3)[jp_];                       \
      float e_ = Q##0 * __uint_as_float(w0_ << 16) + Q##1 * __uint_as_float(w1_ << 16) + \
                 Q##2 * __uint_as_float(w2_ << 16) + Q##3 * __uint_as_float(w3_ << 16);  \
      float o_ = Q##0 * __uint_as_float(w0_ & 0xffff0000u) + Q##1 * __uint_as_float(w1_ & 0xffff0000u) + \
                 Q##2 * __uint_as_float(w2_ & 0xffff0000u) + Q##3 * __uint_as_float(w3_ & 0xffff0000u);  \
      unsigned p_;                                                      \
      asm("v_cvt_pk_bf16_f32 %0, %1, %2" : "=v"(p_) : "v"(e_), "v"(o_)); \
      rr_[jp_] = p_;                                                    \
    }                                                                   \
    *(int4*)(&At[(c) & 1][0] + (WB)) = *(int4*)rr_;                     \
  } while (0)

#define DC_COMMIT(c, V, Q)                                  \
  do {                                                      \
    DC_HALF(c, V##00, V##01, V##02, V##03, Q, wbyte0);      \
    DC_HALF(c, V##10, V##11, V##12, V##13, Q, wbyte1);      \
  } while (0)

#define LDS_BARRIER()                                        \
  do {                                                       \
    asm volatile("s_waitcnt lgkmcnt(0)" ::: "memory");       \
    __builtin_amdgcn_s_barrier();                            \
  } while (0)

__global__ __launch_bounds__(512, 2) void k_dconv(const unsigned short* __restrict__ xb,
                                                  const float* __restrict__ off,
                                                  const unsigned short* __restrict__ wt,
                                                  float* __restrict__ y1p,
                                                  float* __restrict__ st1, float* __restrict__ st2) {
  __shared__ unsigned int sidx[18][64][4];
  __shared__ float swt[18][64][4];
  __shared__ char At[2][16384];  // [64 px][128 ch] bf16, XOR-swizzled, double-buffered
  int t = threadIdx.x;
  int l = t & 63, og = t >> 6;  // wave == o-slice
  int bid = blockIdx.x;
  int id8 = (bid & 7) * 32 + (bid >> 3);  // XCD swizzle (256 % 8 == 0)
  int pixb = id8 * 64;                    // full 64-px row
  int b = id8 >> 6, h = id8 & 63;

  for (int id = t; id < 1152; id += 512) {
    int chunk = id >> 6, ppx = id & 63;
    int g = chunk / 9, kk = chunk % 9;
    const float* op = off + (size_t)(pixb + ppx) * 54;
    float dy = op[(g * 9 + kk) * 2];
    float dx = op[(g * 9 + kk) * 2 + 1];
    float msk = op[36 + g * 9 + kk];
    float py = dy + (float)(h + kk / 3 - 1);
    float pxf = dx + (float)(ppx + kk % 3 - 1);
    float y0f = floorf(py), x0f = floorf(pxf);
    float ly = py - y0f, lx = pxf - x0f;
    int y0 = (int)y0f, x0 = (int)x0f;
    int y1 = y0 + 1, x1 = x0 + 1;
    float oky0 = (y0 >= 0 && y0 < 64) ? 1.f : 0.f;
    float oky1 = (y1 >= 0 && y1 < 64) ? 1.f : 0.f;
    float okx0 = (x0 >= 0 && x0 < 64) ? 1.f : 0.f;
    float okx1 = (x1 >= 0 && x1 < 64) ? 1.f : 0.f;
    int y0c = min(max(y0, 0), 63), y1c = min(max(y1, 0), 63);
    int x0c = min(max(x0, 0), 63), x1c = min(max(x1, 0), 63);
    unsigned base = (unsigned)(b * 4096);
    unsigned gofs = (unsigned)(g * 128);
    sidx[chunk][ppx][0] = (base + y0c * 64 + x0c) * 256u + gofs;
    sidx[chunk][ppx][1] = (base + y0c * 64 + x1c) * 256u + gofs;
    sidx[chunk][ppx][2] = (base + y1c * 64 + x0c) * 256u + gofs;
    sidx[chunk][ppx][3] = (base + y1c * 64 + x1c) * 256u + gofs;
    swt[chunk][ppx][0] = (1.f - ly) * (1.f - lx) * oky0 * okx0 * msk;
    swt[chunk][ppx][1] = (1.f - ly) * lx * oky0 * okx1 * msk;
    swt[chunk][ppx][2] = ly * (1.f - lx) * oky1 * okx0 * msk;
    swt[chunk][ppx][3] = ly * lx * oky1 * okx1 * msk;
  }
  __syncthreads();

  int px = t >> 3;                 // 0..63
  int cq = t & 7;                  // 8 ch-slices of 16
  unsigned chof0 = cq * 16u, chof1 = cq * 16u + 8u;
  int wbyte0 = (px * 256 + cq * 32) ^ ((px & 7) << 4);
  int wbyte1 = (px * 256 + cq * 32 + 16) ^ ((px & 7) << 4);
  int khi = l >> 4, lo = l & 15;

  s8v va00, va01, va02, va03, va10, va11, va12, va13;
  s8v vb00, vb01, vb02, vb03, vb10, vb11, vb12, vb13;
  float qa0, qa1, qa2, qa3, qb0, qb1, qb2, qb3;

  DC_ISSUE(0, va, qa);
  DC_ISSUE(1, vb, qb);
  DC_COMMIT(0, va, qa);
  LDS_BARRIER();

  f4v zero = {0.f, 0.f, 0.f, 0.f};
  f4v acc[4] = {zero, zero, zero, zero};

  for (int c = 0; c < 18; ++c) {
    if (c < 16) {
      if ((c & 1) == 0) DC_ISSUE(c + 2, va, qa);
      else              DC_ISSUE(c + 2, vb, qb);
    }
#pragma unroll
    for (int ks4 = 0; ks4 < 4; ++ks4) {
      int kstep = c * 4 + ks4;
      s8v bfr = *(const s8v*)&wt[((size_t)(kstep * 8 + og) * 64 + l) * 8];
      int chb = ks4 * 64 + khi * 16;
#pragma unroll
      for (int m = 0; m < 4; ++m) {
        int trA = m * 16 + lo;
        int rbyte = (trA * 256 + chb) ^ ((trA & 7) << 4);
        s8v a = *(const s8v*)(&At[c & 1][0] + rbyte);
        acc[m] = __builtin_amdgcn_mfma_f32_16x16x32_bf16(a, bfr, acc[m], 0, 0, 0);
      }
    }
    if (c < 17) {
      if ((c & 1) == 0) DC_COMMIT(c + 1, vb, qb);
      else              DC_COMMIT(c + 1, va, qa);
    }
    LDS_BARRIER();
  }

  // epilogue: y1p write + fused stats
  int o = og * 16 + lo;
  float s1v = 0.f, s2v = 0.f;
#pragma unroll
  for (int m = 0; m < 4; ++m)
#pragma unroll
    for (int j = 0; j < 4; ++j) {
      float vv = acc[m][j];
      y1p[(size_t)(pixb + m * 16 + khi * 4 + j) * 128 + o] = vv;
      s1v += vv; s2v += vv * vv;
    }
  float* red = &swt[0][0][0];
  red[khi * 128 + o] = s1v;
  red[512 + khi * 128 + o] = s2v;
  __syncthreads();
  if (t < 128) {
    float a1 = 0.f, a2 = 0.f;
#pragma unroll
    for (int rr = 0; rr < 4; ++rr) { a1 += red[rr * 128 + t]; a2 += red[512 + rr * 128 + t]; }
    atomicAdd(&st1[t], a1);
    atomicAdd(&st2[t], a2);
  }
}

// ---------------- bn1 + relu: f32 NHWC -> bf16 NHWC ----------------
__global__ __launch_bounds__(256) void k_bnrelu1(const float* __restrict__ yp, const float* __restrict__ s1,
                                                 const float* __restrict__ s2, const float* __restrict__ g,
                                                 const float* __restrict__ bb, unsigned short* __restrict__ yb) {
  __shared__ float sc[128], sh[128];
  int t = threadIdx.x;
  if (t < 128) {
    float m = s1[t] * (1.f / 16384.f);
    float var = s2[t] * (1.f / 16384.f) - m * m;
    float s = g[t] * rsqrtf(var + EPSBN);
    sc[t] = s;
    sh[t] = bb[t] - m * s;
  }
  __syncthreads();
  size_t i = ((size_t)blockIdx.x * 256 + t) * 8;
  int c0 = (int)(i & 127);
  float4 u = *(const float4*)&yp[i];
  float4 v = *(const float4*)&yp[i + 4];
  s8v r;
  r[0] = (short)f2bf(fmaxf(0.f, u.x * sc[c0 + 0] + sh[c0 + 0]));
  r[1] = (short)f2bf(fmaxf(0.f, u.y * sc[c0 + 1] + sh[c0 + 1]));
  r[2] = (short)f2bf(fmaxf(0.f, u.z * sc[c0 + 2] + sh[c0 + 2]));
  r[3] = (short)f2bf(fmaxf(0.f, u.w * sc[c0 + 3] + sh[c0 + 3]));
  r[4] = (short)f2bf(fmaxf(0.f, v.x * sc[c0 + 4] + sh[c0 + 4]));
  r[5] = (short)f2bf(fmaxf(0.f, v.y * sc[c0 + 5] + sh[c0 + 5]));
  r[6] = (short)f2bf(fmaxf(0.f, v.z * sc[c0 + 6] + sh[c0 + 6]));
  r[7] = (short)f2bf(fmaxf(0.f, v.w * sc[c0 + 7] + sh[c0 + 7]));
  *(s8v*)&yb[i] = r;
}

// ---------------- conv2: waves = og(8), M=32, fused stats (unchanged) ----------------
__global__ __launch_bounds__(512, 3) void k_conv2(const unsigned short* __restrict__ yb,
                                                  const unsigned short* __restrict__ wt,
                                                  float* __restrict__ y2p,
                                                  float* __restrict__ st1, float* __restrict__ st2) {
  __shared__ char Bs[102 * 256];
  int bid = blockIdx.x;
  int id8 = (bid & 7) * 64 + (bid >> 3);
  int w0 = (id8 & 1) * 32;
  int h = (id8 >> 1) & 63;
  int b = id8 >> 7;
  int t = threadIdx.x;
  int l = t & 63, og = t >> 6;
  f4v zero = {0.f, 0.f, 0.f, 0.f};
  f4v acc[2] = {zero, zero};

  for (int id = t; id < 1632; id += 512) {
    int tr = id >> 4, oq = id & 15;
    int ky = tr / 34, col = tr % 34;
    int hh = h + ky - 1, ww = w0 + col - 1;
    s8v val = {0, 0, 0, 0, 0, 0, 0, 0};
    if ((unsigned)hh < 64u && (unsigned)ww < 64u)
      val = *(const s8v*)&yb[(((size_t)(b * 64 + hh)) * 64 + ww) * 128 + oq * 8];
    int byte = (tr * 256 + oq * 16) ^ ((tr & 7) << 4);
    *(s8v*)(Bs + byte) = val;
  }
  __syncthreads();
  int khi = l >> 4, lo = l & 15;
#pragma unroll
  for (int tap = 0; tap < 9; ++tap) {
    int ky = tap / 3, kx = tap % 3;
#pragma unroll
    for (int ks4 = 0; ks4 < 4; ++ks4) {
      int kstep = ((ks4 >> 1) * 9 + tap) * 2 + (ks4 & 1);
      s8v bfr = *(const s8v*)&wt[((size_t)(kstep * 8 + og) * 64 + l) * 8];
      int chb = ks4 * 64 + khi * 16;
#pragma unroll
      for (int m = 0; m < 2; ++m) {
        int tr = ky * 34 + m * 16 + lo + kx;
        int rbyte = (tr * 256 + chb) ^ ((tr & 7) << 4);
        s8v a = *(const s8v*)(Bs + rbyte);
        acc[m] = __builtin_amdgcn_mfma_f32_16x16x32_bf16(a, bfr, acc[m], 0, 0, 0);
      }
    }
  }
  __syncthreads();
  int pixb = (b * 64 + h) * 64 + w0;
  int o = og * 16 + lo;
  float s1v = 0.f, s2v = 0.f;
#pragma unroll
  for (int m = 0; m < 2; ++m)
#pragma unroll
    for (int j = 0; j < 4; ++j) {
      float vv = acc[m][j];
      y2p[(size_t)(pixb + m * 16 + khi * 4 + j) * 128 + o] = vv;
      s1v += vv; s2v += vv * vv;
    }
  float* red = (float*)Bs;
  red[khi * 128 + o] = s1v;
  red[512 + khi * 128 + o] = s2v;
  __syncthreads();
  if (t < 128) {
    float a1 = 0.f, a2 = 0.f;
#pragma unroll
    for (int rr = 0; rr < 4; ++rr) { a1 += red[rr * 128 + t]; a2 += red[512 + rr * 128 + t]; }
    atomicAdd(&st1[t], a1);
    atomicAdd(&st2[t], a2);
  }
}

// ---------------- bn2 + relu + NHWC -> NCHW (LDS-transposed, both sides coalesced) ----------------
__global__ __launch_bounds__(256) void k_bnrelu2(const float* __restrict__ yp, const float* __restrict__ s1,
                                                 const float* __restrict__ s2, const float* __restrict__ g,
                                                 const float* __restrict__ bb, float* __restrict__ out) {
  __shared__ float sc[128], sh[128];
  __shared__ float buf[64 * 129];
  int t = threadIdx.x;
  if (t < 128) {
    float m = s1[t] * (1.f / 16384.f);
    float var = s2[t] * (1.f / 16384.f) - m * m;
    float s = g[t] * rsqrtf(var + EPSBN);
    sc[t] = s;
    sh[t] = bb[t] - m * s;
  }
  int bh = blockIdx.x;
  int b = bh >> 6, h = bh & 63;
  const float* src = yp + (size_t)bh * 8192;
  for (int i = t; i < 2048; i += 256) {
    float4 v = ((const float4*)src)[i];
    int w = (i * 4) >> 7, o = (i * 4) & 127;
    float* d = &buf[w * 129 + o];
    d[0] = v.x; d[1] = v.y; d[2] = v.z; d[3] = v.w;
  }
  __syncthreads();
  for (int id = t; id < 8192; id += 256) {
    int o = id >> 6, w = id & 63;
    float v = buf[w * 129 + o];
    v = fmaxf(0.f, v * sc[o] + sh[o]);
    out[(((size_t)b * 128 + o) * 64 + h) * 64 + w] = v;
  }
}

extern "C" void kernel_launch(void* const* d_in, const int* in_sizes, int n_in,
                              void* d_out, int out_size, void* d_ws, size_t ws_size,
                              hipStream_t stream) {
  const float* in_v = (const float*)d_in[0];
  const float* in_i = (const float*)d_in[1];
  const float* off_w = (const float*)d_in[2];
  const float* off_b = (const float*)d_in[3];
  const float* dconv_w = (const float*)d_in[4];
  const float* bn1_g = (const float*)d_in[5];
  const float* bn1_b = (const float*)d_in[6];
  const float* conv2_w = (const float*)d_in[7];
  const float* bn2_g = (const float*)d_in[8];
  const float* bn2_b = (const float*)d_in[9];
  float* out = (float*)d_out;

  char* w = (char*)d_ws;
  unsigned short* xb = (unsigned short*)w;      w += (size_t)16384 * 256 * 2;  // 8 MB
  float* off_nhwc = (float*)w;                  w += (size_t)16384 * 54 * 4;   // 3.4 MB
  unsigned short* wtf_off = (unsigned short*)w; w += (size_t)18432 * 8 * 2;    // 288 KB
  unsigned short* wtf_d = (unsigned short*)w;   w += (size_t)36864 * 8 * 2;    // 576 KB
  unsigned short* wtf_2 = (unsigned short*)w;   w += (size_t)18432 * 8 * 2;    // 288 KB
  float* y1p = (float*)w;                       w += (size_t)16384 * 128 * 4;  // 8 MB
  unsigned short* y1b = (unsigned short*)w;     w += (size_t)16384 * 128 * 2;  // 4 MB
  float* y2p = (float*)w;                       w += (size_t)16384 * 128 * 4;  // 8 MB
  float* stats = (float*)w;                     w += 512 * 4;

  hipMemsetAsync(stats, 0, 512 * 4, stream);
  k_pack<<<dim3(128, 4, 4), dim3(32, 8), 0, stream>>>(in_v, in_i, xb);
  k_wprep_all<<<288, 256, 0, stream>>>(off_w, dconv_w, conv2_w, wtf_off, wtf_d, wtf_2);
  k_offconv<<<512, 512, 0, stream>>>(xb, wtf_off, off_b, off_nhwc);
  k_dconv<<<256, 512, 0, stream>>>(xb, off_nhwc, wtf_d, y1p, stats, stats + 128);
  k_bnrelu1<<<1024, 256, 0, stream>>>(y1p, stats, stats + 128, bn1_g, bn1_b, y1b);
  k_conv2<<<512, 512, 0, stream>>>(y1b, wtf_2, y2p, stats + 256, stats + 384);
  k_bnrelu2<<<256, 256, 0, stream>>>(y2p, stats + 256, stats + 384, bn2_g, bn2_b, out);
}

// Round 10
// 166.237 us; speedup vs baseline: 1.0604x; 1.0604x over previous
//
#include <hip/hip_runtime.h>

#define EPSBN 1e-5f

using s8v = __attribute__((ext_vector_type(8))) short;
using f4v = __attribute__((ext_vector_type(4))) float;

__device__ inline unsigned short f2bf(float f) {
  unsigned u = __float_as_uint(f);
  return (unsigned short)((u + 0x7FFFu + ((u >> 16) & 1u)) >> 16);
}

// ---------------- pack: concat(v,i) + NCHW f32 -> NHWC bf16 ----------------
__global__ __launch_bounds__(256) void k_pack(const float* __restrict__ v, const float* __restrict__ im,
                                              unsigned short* __restrict__ xb) {
  __shared__ float tile[64][33];
  int b = blockIdx.z;
  int hw0 = blockIdx.x * 32;
  int c0 = blockIdx.y * 64;
  int tx = threadIdx.x, ty = threadIdx.y;
#pragma unroll
  for (int i = 0; i < 64; i += 8) {
    int c = c0 + ty + i;
    const float* src = (c < 128) ? (v + ((size_t)b * 128 + c) * 4096)
                                 : (im + ((size_t)b * 128 + (c - 128)) * 4096);
    tile[ty + i][tx] = src[hw0 + tx];
  }
  __syncthreads();
#pragma unroll
  for (int i = 0; i < 32; i += 8) {
    int hw = hw0 + ty + i;
    ushort2 o;
    o.x = f2bf(tile[2 * tx][ty + i]);
    o.y = f2bf(tile[2 * tx + 1][ty + i]);
    *(ushort2*)&xb[((size_t)(b * 4096 + hw)) * 256 + c0 + 2 * tx] = o;
  }
}

// ---------------- merged weight prep: fragment-major bf16 (verified mappings) ----------------
__global__ __launch_bounds__(256) void k_wprep_all(const float* __restrict__ w_off,
                                                   const float* __restrict__ w_d,
                                                   const float* __restrict__ w_2,
                                                   unsigned short* __restrict__ wt_off,
                                                   unsigned short* __restrict__ wt_d,
                                                   unsigned short* __restrict__ wt_2) {
  int bid = blockIdx.x, t = threadIdx.x;
  if (bid < 72) {
    int id = bid * 256 + t;
    int lane = id & 63;
    int nb = (id >> 6) & 3;
    int ks = id >> 8;
    int ks2 = ks & 1, tap = (ks >> 1) % 9, cc = ks / 18;
    int o = nb * 16 + (lane & 15);
    int cb = cc * 64 + ks2 * 32 + ((lane >> 4) * 8);
    s8v r;
#pragma unroll
    for (int j = 0; j < 8; ++j) {
      float val = (o < 54) ? w_off[((size_t)o * 256 + cb + j) * 9 + tap] : 0.f;
      r[j] = (short)f2bf(val);
    }
    *(s8v*)&wt_off[(size_t)id * 8] = r;
  } else if (bid < 216) {
    int id = (bid - 72) * 256 + t;
    int lane = id & 63;
    int nb = (id >> 6) & 7;
    int kstep = id >> 9;
    int chunk = kstep >> 2, ks4 = kstep & 3;
    int g = chunk / 9, kk = chunk % 9;
    int o = nb * 16 + (lane & 15);
    int cb = g * 128 + ks4 * 32 + ((lane >> 4) * 8);
    s8v r;
#pragma unroll
    for (int j = 0; j < 8; ++j) r[j] = (short)f2bf(w_d[((size_t)o * 256 + cb + j) * 9 + kk]);
    *(s8v*)&wt_d[(size_t)id * 8] = r;
  } else {
    int id = (bid - 216) * 256 + t;
    int lane = id & 63;
    int nb = (id >> 6) & 7;
    int kstep = id >> 9;
    int ks2 = kstep & 1, tap = (kstep >> 1) % 9, cc = kstep / 18;
    int o = nb * 16 + (lane & 15);
    int cb = cc * 64 + ks2 * 32 + ((lane >> 4) * 8);
    s8v r;
#pragma unroll
    for (int j = 0; j < 8; ++j) r[j] = (short)f2bf(w_2[((size_t)o * 128 + cb + j) * 9 + tap]);
    *(s8v*)&wt_2[(size_t)id * 8] = r;
  }
}

// ---------------- offset conv: waves = og(4) x kh(2), M=32 (unchanged) ----------------
__global__ __launch_bounds__(512, 3) void k_offconv(const unsigned short* __restrict__ xb,
                                                    const unsigned short* __restrict__ wt,
                                                    const float* __restrict__ bias,
                                                    float* __restrict__ off) {
  __shared__ char Xs[102 * 512];
  __shared__ float redx[2048];
  int bid = blockIdx.x;
  int id8 = (bid & 7) * 64 + (bid >> 3);
  int w0 = (id8 & 1) * 32;
  int h = (id8 >> 1) & 63;
  int b = id8 >> 7;
  int t = threadIdx.x;
  int l = t & 63, wv = t >> 6;
  int og = wv & 3, kh = wv >> 2;
  f4v zero = {0.f, 0.f, 0.f, 0.f};
  f4v acc[2] = {zero, zero};

  for (int id = t; id < 3264; id += 512) {
    int tr = id >> 5, oq8 = id & 31;
    int ky = tr / 34, col = tr % 34;
    int hh = h + ky - 1, ww = w0 + col - 1;
    s8v val = {0, 0, 0, 0, 0, 0, 0, 0};
    if ((unsigned)hh < 64u && (unsigned)ww < 64u)
      val = *(const s8v*)&xb[(((size_t)(b * 64 + hh)) * 64 + ww) * 256 + oq8 * 8];
    int byte = (tr * 512 + oq8 * 16) ^ ((tr & 7) << 4);
    *(s8v*)(Xs + byte) = val;
  }
  __syncthreads();
  int khi = l >> 4, lo = l & 15;
#pragma unroll
  for (int tap = 0; tap < 9; ++tap) {
    int ky = tap / 3, kx = tap % 3;
#pragma unroll
    for (int s = 0; s < 4; ++s) {
      int cc = kh * 2 + (s >> 1);
      int ks2 = s & 1;
      int kstep = cc * 18 + tap * 2 + ks2;
      int chb = cc * 128 + ks2 * 64 + khi * 16;
      s8v bfr = *(const s8v*)&wt[((size_t)(kstep * 4 + og) * 64 + l) * 8];
#pragma unroll
      for (int m = 0; m < 2; ++m) {
        int tr = ky * 34 + m * 16 + lo + kx;
        int rbyte = (tr * 512 + chb) ^ ((tr & 7) << 4);
        s8v a = *(const s8v*)(Xs + rbyte);
        acc[m] = __builtin_amdgcn_mfma_f32_16x16x32_bf16(a, bfr, acc[m], 0, 0, 0);
      }
    }
  }
  if (kh == 1) {
#pragma unroll
    for (int m = 0; m < 2; ++m)
#pragma unroll
      for (int j = 0; j < 4; ++j) redx[((og * 64 + l) * 2 + m) * 4 + j] = acc[m][j];
  }
  __syncthreads();
  if (kh == 0) {
    int o = og * 16 + lo;
    int pixb = (b * 64 + h) * 64 + w0;
    if (o < 54) {
      float bi = bias[o];
#pragma unroll
      for (int m = 0; m < 2; ++m)
#pragma unroll
        for (int j = 0; j < 4; ++j) {
          int px = pixb + m * 16 + khi * 4 + j;
          float vv = acc[m][j] + redx[((og * 64 + l) * 2 + m) * 4 + j] + bi;
          if (o >= 36) vv = 1.f / (1.f + __expf(-vv));
          off[(size_t)px * 54 + o] = vv;
        }
    }
  }
}

// ---------------- deform sample + dconv: 3-deep pipeline, triple-buffered LDS ----------------
#define DC_ISSUE(c, V, Q)                                   \
  do {                                                      \
    const unsigned* ip_ = sidx[(c)][px];                    \
    const float* qp_ = swt[(c)][px];                        \
    Q##0 = qp_[0]; Q##1 = qp_[1]; Q##2 = qp_[2]; Q##3 = qp_[3]; \
    V##0 = *(const s8v*)&xb[ip_[0] + chof];                 \
    V##1 = *(const s8v*)&xb[ip_[1] + chof];                 \
    V##2 = *(const s8v*)&xb[ip_[2] + chof];                 \
    V##3 = *(const s8v*)&xb[ip_[3] + chof];                 \
  } while (0)

// blend 4 taps (packed-u32 bf16 trick) and store 16B to LDS buffer BUF
#define DC_COMMIT(BUF, V, Q)                                            \
  do {                                                                  \
    unsigned rr_[4];                                                    \
    _Pragma("unroll") for (int jp_ = 0; jp_ < 4; ++jp_) {               \
      unsigned w0_ = ((const unsigned*)&V##0)[jp_];                     \
      unsigned w1_ = ((const unsigned*)&V##1)[jp_];                     \
      unsigned w2_ = ((const unsigned*)&V##2)[jp_];                     \
      unsigned w3_ = ((const unsigned*)&V##3)[jp_];                     \
      float e_ = Q##0 * __uint_as_float(w0_ << 16) + Q##1 * __uint_as_float(w1_ << 16) + \
                 Q##2 * __uint_as_float(w2_ << 16) + Q##3 * __uint_as_float(w3_ << 16);  \
      float o_ = Q##0 * __uint_as_float(w0_ & 0xffff0000u) + Q##1 * __uint_as_float(w1_ & 0xffff0000u) + \
                 Q##2 * __uint_as_float(w2_ & 0xffff0000u) + Q##3 * __uint_as_float(w3_ & 0xffff0000u);  \
      unsigned p_;                                                      \
      asm("v_cvt_pk_bf16_f32 %0, %1, %2" : "=v"(p_) : "v"(e_), "v"(o_)); \
      rr_[jp_] = p_;                                                    \
    }                                                                   \
    *(int4*)(&At[BUF][0] + wbyte) = *(int4*)rr_;                        \
  } while (0)

#define LDS_BARRIER()                                        \
  do {                                                       \
    asm volatile("s_waitcnt lgkmcnt(0)" ::: "memory");       \
    __builtin_amdgcn_s_barrier();                            \
  } while (0)

// MFMA over chunk C from buffer BUF (BUF compile-time)
#define DC_MFMA(C, BUF)                                                 \
  do {                                                                  \
    __builtin_amdgcn_s_setprio(1);                                      \
    _Pragma("unroll") for (int ks4_ = 0; ks4_ < 4; ++ks4_) {            \
      int kstep_ = (C) * 4 + ks4_;                                      \
      s8v bfr_ = *(const s8v*)&wt[((size_t)(kstep_ * 8 + og) * 64 + l) * 8]; \
      int chb_ = ks4_ * 64 + khi * 16;                                  \
      _Pragma("unroll") for (int m_ = 0; m_ < 2; ++m_) {                \
        int trA_ = m_ * 16 + lo;                                        \
        int rbyte_ = (trA_ * 256 + chb_) ^ ((trA_ & 7) << 4);           \
        s8v a_ = *(const s8v*)(&At[BUF][0] + rbyte_);                   \
        acc[m_] = __builtin_amdgcn_mfma_f32_16x16x32_bf16(a_, bfr_, acc[m_], 0, 0, 0); \
      }                                                                 \
    }                                                                   \
    __builtin_amdgcn_s_setprio(0);                                      \
  } while (0)

// one pipeline phase: issue c+3, MFMA c, commit c+1, barrier
#define DC_PHASE(C, BUF, VI, QI, VC, QC, BUFC)               \
  do {                                                       \
    if ((C) < 15) DC_ISSUE((C) + 3, VI, QI);                 \
    DC_MFMA(C, BUF);                                         \
    if ((C) < 17) DC_COMMIT(BUFC, VC, QC);                   \
    LDS_BARRIER();                                           \
  } while (0)

__global__ __launch_bounds__(512, 4) void k_dconv(const unsigned short* __restrict__ xb,
                                                  const float* __restrict__ off,
                                                  const unsigned short* __restrict__ wt,
                                                  float* __restrict__ y1p,
                                                  float* __restrict__ st1, float* __restrict__ st2) {
  __shared__ unsigned int sidx[18][32][4];
  __shared__ float swt[18][32][4];
  __shared__ char At[3][8192];  // [32 px][128 ch] bf16, XOR-swizzled, triple-buffered
  int t = threadIdx.x;
  int l = t & 63, og = t >> 6;  // wave == o-slice
  int bid = blockIdx.x;
  int id8 = (bid & 7) * 64 + (bid >> 3);  // XCD swizzle (512 % 8 == 0)
  int pixb = id8 * 32;
  int b = pixb >> 12, h = (pixb >> 6) & 63, w0 = pixb & 63;

  for (int id = t; id < 576; id += 512) {
    int chunk = id >> 5, ppx = id & 31;
    int g = chunk / 9, kk = chunk % 9;
    const float* op = off + (size_t)(pixb + ppx) * 54;
    float dy = op[(g * 9 + kk) * 2];
    float dx = op[(g * 9 + kk) * 2 + 1];
    float msk = op[36 + g * 9 + kk];
    float py = dy + (float)(h + kk / 3 - 1);
    float pxf = dx + (float)(w0 + ppx + kk % 3 - 1);
    float y0f = floorf(py), x0f = floorf(pxf);
    float ly = py - y0f, lx = pxf - x0f;
    int y0 = (int)y0f, x0 = (int)x0f;
    int y1 = y0 + 1, x1 = x0 + 1;
    float oky0 = (y0 >= 0 && y0 < 64) ? 1.f : 0.f;
    float oky1 = (y1 >= 0 && y1 < 64) ? 1.f : 0.f;
    float okx0 = (x0 >= 0 && x0 < 64) ? 1.f : 0.f;
    float okx1 = (x1 >= 0 && x1 < 64) ? 1.f : 0.f;
    int y0c = min(max(y0, 0), 63), y1c = min(max(y1, 0), 63);
    int x0c = min(max(x0, 0), 63), x1c = min(max(x1, 0), 63);
    unsigned base = (unsigned)(b * 4096);
    unsigned gofs = (unsigned)(g * 128);
    sidx[chunk][ppx][0] = (base + y0c * 64 + x0c) * 256u + gofs;
    sidx[chunk][ppx][1] = (base + y0c * 64 + x1c) * 256u + gofs;
    sidx[chunk][ppx][2] = (base + y1c * 64 + x0c) * 256u + gofs;
    sidx[chunk][ppx][3] = (base + y1c * 64 + x1c) * 256u + gofs;
    swt[chunk][ppx][0] = (1.f - ly) * (1.f - lx) * oky0 * okx0 * msk;
    swt[chunk][ppx][1] = (1.f - ly) * lx * oky0 * okx1 * msk;
    swt[chunk][ppx][2] = ly * (1.f - lx) * oky1 * okx0 * msk;
    swt[chunk][ppx][3] = ly * lx * oky1 * okx1 * msk;
  }
  __syncthreads();

  int px = t >> 4, oq = t & 15;
  unsigned chof = oq * 8u;
  int wbyte = (px * 256 + oq * 16) ^ ((px & 7) << 4);
  int khi = l >> 4, lo = l & 15;

  s8v va0, va1, va2, va3, vb0, vb1, vb2, vb3, vc0, vc1, vc2, vc3;
  float qa0, qa1, qa2, qa3, qb0, qb1, qb2, qb3, qc0, qc1, qc2, qc3;

  // prologue: 3 chunks in flight before first MFMA
  DC_ISSUE(0, va, qa);
  DC_ISSUE(1, vb, qb);
  DC_ISSUE(2, vc, qc);
  DC_COMMIT(0, va, qa);
  LDS_BARRIER();

  f4v zero = {0.f, 0.f, 0.f, 0.f};
  f4v acc[2] = {zero, zero};

  for (int cb = 0; cb < 6; ++cb) {
    int c0 = cb * 3;
    DC_PHASE(c0 + 0, 0, va, qa, vb, qb, 1);
    DC_PHASE(c0 + 1, 1, vb, qb, vc, qc, 2);
    DC_PHASE(c0 + 2, 2, vc, qc, va, qa, 0);
  }

  // epilogue: y1p write + fused stats
  int o = og * 16 + lo;
  float s1v = 0.f, s2v = 0.f;
#pragma unroll
  for (int m = 0; m < 2; ++m)
#pragma unroll
    for (int j = 0; j < 4; ++j) {
      float vv = acc[m][j];
      y1p[(size_t)(pixb + m * 16 + khi * 4 + j) * 128 + o] = vv;
      s1v += vv; s2v += vv * vv;
    }
  float* red = &swt[0][0][0];
  red[khi * 128 + o] = s1v;
  red[512 + khi * 128 + o] = s2v;
  __syncthreads();
  if (t < 128) {
    float a1 = 0.f, a2 = 0.f;
#pragma unroll
    for (int rr = 0; rr < 4; ++rr) { a1 += red[rr * 128 + t]; a2 += red[512 + rr * 128 + t]; }
    atomicAdd(&st1[t], a1);
    atomicAdd(&st2[t], a2);
  }
}

// ---------------- bn1 + relu: f32 NHWC -> bf16 NHWC ----------------
__global__ __launch_bounds__(256) void k_bnrelu1(const float* __restrict__ yp, const float* __restrict__ s1,
                                                 const float* __restrict__ s2, const float* __restrict__ g,
                                                 const float* __restrict__ bb, unsigned short* __restrict__ yb) {
  __shared__ float sc[128], sh[128];
  int t = threadIdx.x;
  if (t < 128) {
    float m = s1[t] * (1.f / 16384.f);
    float var = s2[t] * (1.f / 16384.f) - m * m;
    float s = g[t] * rsqrtf(var + EPSBN);
    sc[t] = s;
    sh[t] = bb[t] - m * s;
  }
  __syncthreads();
  size_t i = ((size_t)blockIdx.x * 256 + t) * 8;
  int c0 = (int)(i & 127);
  float4 u = *(const float4*)&yp[i];
  float4 v = *(const float4*)&yp[i + 4];
  s8v r;
  r[0] = (short)f2bf(fmaxf(0.f, u.x * sc[c0 + 0] + sh[c0 + 0]));
  r[1] = (short)f2bf(fmaxf(0.f, u.y * sc[c0 + 1] + sh[c0 + 1]));
  r[2] = (short)f2bf(fmaxf(0.f, u.z * sc[c0 + 2] + sh[c0 + 2]));
  r[3] = (short)f2bf(fmaxf(0.f, u.w * sc[c0 + 3] + sh[c0 + 3]));
  r[4] = (short)f2bf(fmaxf(0.f, v.x * sc[c0 + 4] + sh[c0 + 4]));
  r[5] = (short)f2bf(fmaxf(0.f, v.y * sc[c0 + 5] + sh[c0 + 5]));
  r[6] = (short)f2bf(fmaxf(0.f, v.z * sc[c0 + 6] + sh[c0 + 6]));
  r[7] = (short)f2bf(fmaxf(0.f, v.w * sc[c0 + 7] + sh[c0 + 7]));
  *(s8v*)&yb[i] = r;
}

// ---------------- conv2: waves = og(8), M=32, fused stats (unchanged) ----------------
__global__ __launch_bounds__(512, 3) void k_conv2(const unsigned short* __restrict__ yb,
                                                  const unsigned short* __restrict__ wt,
                                                  float* __restrict__ y2p,
                                                  float* __restrict__ st1, float* __restrict__ st2) {
  __shared__ char Bs[102 * 256];
  int bid = blockIdx.x;
  int id8 = (bid & 7) * 64 + (bid >> 3);
  int w0 = (id8 & 1) * 32;
  int h = (id8 >> 1) & 63;
  int b = id8 >> 7;
  int t = threadIdx.x;
  int l = t & 63, og = t >> 6;
  f4v zero = {0.f, 0.f, 0.f, 0.f};
  f4v acc[2] = {zero, zero};

  for (int id = t; id < 1632; id += 512) {
    int tr = id >> 4, oq = id & 15;
    int ky = tr / 34, col = tr % 34;
    int hh = h + ky - 1, ww = w0 + col - 1;
    s8v val = {0, 0, 0, 0, 0, 0, 0, 0};
    if ((unsigned)hh < 64u && (unsigned)ww < 64u)
      val = *(const s8v*)&yb[(((size_t)(b * 64 + hh)) * 64 + ww) * 128 + oq * 8];
    int byte = (tr * 256 + oq * 16) ^ ((tr & 7) << 4);
    *(s8v*)(Bs + byte) = val;
  }
  __syncthreads();
  int khi = l >> 4, lo = l & 15;
#pragma unroll
  for (int tap = 0; tap < 9; ++tap) {
    int ky = tap / 3, kx = tap % 3;
#pragma unroll
    for (int ks4 = 0; ks4 < 4; ++ks4) {
      int kstep = ((ks4 >> 1) * 9 + tap) * 2 + (ks4 & 1);
      s8v bfr = *(const s8v*)&wt[((size_t)(kstep * 8 + og) * 64 + l) * 8];
      int chb = ks4 * 64 + khi * 16;
#pragma unroll
      for (int m = 0; m < 2; ++m) {
        int tr = ky * 34 + m * 16 + lo + kx;
        int rbyte = (tr * 256 + chb) ^ ((tr & 7) << 4);
        s8v a = *(const s8v*)(Bs + rbyte);
        acc[m] = __builtin_amdgcn_mfma_f32_16x16x32_bf16(a, bfr, acc[m], 0, 0, 0);
      }
    }
  }
  __syncthreads();
  int pixb = (b * 64 + h) * 64 + w0;
  int o = og * 16 + lo;
  float s1v = 0.f, s2v = 0.f;
#pragma unroll
  for (int m = 0; m < 2; ++m)
#pragma unroll
    for (int j = 0; j < 4; ++j) {
      float vv = acc[m][j];
      y2p[(size_t)(pixb + m * 16 + khi * 4 + j) * 128 + o] = vv;
      s1v += vv; s2v += vv * vv;
    }
  float* red = (float*)Bs;
  red[khi * 128 + o] = s1v;
  red[512 + khi * 128 + o] = s2v;
  __syncthreads();
  if (t < 128) {
    float a1 = 0.f, a2 = 0.f;
#pragma unroll
    for (int rr = 0; rr < 4; ++rr) { a1 += red[rr * 128 + t]; a2 += red[512 + rr * 128 + t]; }
    atomicAdd(&st1[t], a1);
    atomicAdd(&st2[t], a2);
  }
}

// ---------------- bn2 + relu + NHWC -> NCHW (LDS-transposed) ----------------
__global__ __launch_bounds__(256) void k_bnrelu2(const float* __restrict__ yp, const float* __restrict__ s1,
                                                 const float* __restrict__ s2, const float* __restrict__ g,
                                                 const float* __restrict__ bb, float* __restrict__ out) {
  __shared__ float sc[128], sh[128];
  __shared__ float buf[64 * 129];
  int t = threadIdx.x;
  if (t < 128) {
    float m = s1[t] * (1.f / 16384.f);
    float var = s2[t] * (1.f / 16384.f) - m * m;
    float s = g[t] * rsqrtf(var + EPSBN);
    sc[t] = s;
    sh[t] = bb[t] - m * s;
  }
  int bh = blockIdx.x;
  int b = bh >> 6, h = bh & 63;
  const float* src = yp + (size_t)bh * 8192;
  for (int i = t; i < 2048; i += 256) {
    float4 v = ((const float4*)src)[i];
    int w = (i * 4) >> 7, o = (i * 4) & 127;
    float* d = &buf[w * 129 + o];
    d[0] = v.x; d[1] = v.y; d[2] = v.z; d[3] = v.w;
  }
  __syncthreads();
  for (int id = t; id < 8192; id += 256) {
    int o = id >> 6, w = id & 63;
    float v = buf[w * 129 + o];
    v = fmaxf(0.f, v * sc[o] + sh[o]);
    out[(((size_t)b * 128 + o) * 64 + h) * 64 + w] = v;
  }
}

extern "C" void kernel_launch(void* const* d_in, const int* in_sizes, int n_in,
                              void* d_out, int out_size, void* d_ws, size_t ws_size,
                              hipStream_t stream) {
  const float* in_v = (const float*)d_in[0];
  const float* in_i = (const float*)d_in[1];
  const float* off_w = (const float*)d_in[2];
  const float* off_b = (const float*)d_in[3];
  const float* dconv_w = (const float*)d_in[4];
  const float* bn1_g = (const float*)d_in[5];
  const float* bn1_b = (const float*)d_in[6];
  const float* conv2_w = (const float*)d_in[7];
  const float* bn2_g = (const float*)d_in[8];
  const float* bn2_b = (const float*)d_in[9];
  float* out = (float*)d_out;

  char* w = (char*)d_ws;
  unsigned short* xb = (unsigned short*)w;      w += (size_t)16384 * 256 * 2;  // 8 MB
  float* off_nhwc = (float*)w;                  w += (size_t)16384 * 54 * 4;   // 3.4 MB
  unsigned short* wtf_off = (unsigned short*)w; w += (size_t)18432 * 8 * 2;    // 288 KB
  unsigned short* wtf_d = (unsigned short*)w;   w += (size_t)36864 * 8 * 2;    // 576 KB
  unsigned short* wtf_2 = (unsigned short*)w;   w += (size_t)18432 * 8 * 2;    // 288 KB
  float* y1p = (float*)w;                       w += (size_t)16384 * 128 * 4;  // 8 MB
  unsigned short* y1b = (unsigned short*)w;     w += (size_t)16384 * 128 * 2;  // 4 MB
  float* y2p = (float*)w;                       w += (size_t)16384 * 128 * 4;  // 8 MB
  float* stats = (float*)w;                     w += 512 * 4;

  hipMemsetAsync(stats, 0, 512 * 4, stream);
  k_pack<<<dim3(128, 4, 4), dim3(32, 8), 0, stream>>>(in_v, in_i, xb);
  k_wprep_all<<<288, 256, 0, stream>>>(off_w, dconv_w, conv2_w, wtf_off, wtf_d, wtf_2);
  k_offconv<<<512, 512, 0, stream>>>(xb, wtf_off, off_b, off_nhwc);
  k_dconv<<<512, 512, 0, stream>>>(xb, off_nhwc, wtf_d, y1p, stats, stats + 128);
  k_bnrelu1<<<1024, 256, 0, stream>>>(y1p, stats, stats + 128, bn1_g, bn1_b, y1b);
  k_conv2<<<512, 512, 0, stream>>>(y1b, wtf_2, y2p, stats + 256, stats + 384);
  k_bnrelu2<<<256, 256, 0, stream>>>(y2p, stats + 256, stats + 384, bn2_g, bn2_b, out);
}

// Round 11
// 162.373 us; speedup vs baseline: 1.0857x; 1.0238x over previous
//
#include <hip/hip_runtime.h>

#define EPSBN 1e-5f

using s8v = __attribute__((ext_vector_type(8))) short;
using f4v = __attribute__((ext_vector_type(4))) float;

__device__ inline unsigned short f2bf(float f) {
  unsigned u = __float_as_uint(f);
  return (unsigned short)((u + 0x7FFFu + ((u >> 16) & 1u)) >> 16);
}
__device__ inline float bf2f(unsigned short h) {
  return __uint_as_float(((unsigned)h) << 16);
}

// ---------------- prep: pack (2048 blocks) + weight-prep (288) + stats-zero (1) ----------------
__global__ __launch_bounds__(256) void k_prep(const float* __restrict__ v, const float* __restrict__ im,
                                              const float* __restrict__ w_off, const float* __restrict__ w_d,
                                              const float* __restrict__ w_2,
                                              unsigned short* __restrict__ xb,
                                              unsigned short* __restrict__ wt_off,
                                              unsigned short* __restrict__ wt_d,
                                              unsigned short* __restrict__ wt_2,
                                              float* __restrict__ stats) {
  int bid = blockIdx.x, t = threadIdx.x;
  if (bid < 2048) {  // pack: concat + NCHW f32 -> NHWC bf16
    __shared__ float tile[64][33];
    int b = bid >> 9;
    int rem = bid & 511;
    int c0 = (rem >> 7) * 64;
    int hw0 = (rem & 127) * 32;
    int tx = t & 31, ty = t >> 5;
#pragma unroll
    for (int i = 0; i < 64; i += 8) {
      int c = c0 + ty + i;
      const float* src = (c < 128) ? (v + ((size_t)b * 128 + c) * 4096)
                                   : (im + ((size_t)b * 128 + (c - 128)) * 4096);
      tile[ty + i][tx] = src[hw0 + tx];
    }
    __syncthreads();
#pragma unroll
    for (int i = 0; i < 32; i += 8) {
      int hw = hw0 + ty + i;
      ushort2 o;
      o.x = f2bf(tile[2 * tx][ty + i]);
      o.y = f2bf(tile[2 * tx + 1][ty + i]);
      *(ushort2*)&xb[((size_t)(b * 4096 + hw)) * 256 + c0 + 2 * tx] = o;
    }
  } else if (bid < 2336) {  // weight prep (verified fragment mappings)
    int wb = bid - 2048;
    if (wb < 72) {
      int id = wb * 256 + t;
      int lane = id & 63;
      int nb = (id >> 6) & 3;
      int ks = id >> 8;
      int ks2 = ks & 1, tap = (ks >> 1) % 9, cc = ks / 18;
      int o = nb * 16 + (lane & 15);
      int cb = cc * 64 + ks2 * 32 + ((lane >> 4) * 8);
      s8v r;
#pragma unroll
      for (int j = 0; j < 8; ++j) {
        float val = (o < 54) ? w_off[((size_t)o * 256 + cb + j) * 9 + tap] : 0.f;
        r[j] = (short)f2bf(val);
      }
      *(s8v*)&wt_off[(size_t)id * 8] = r;
    } else if (wb < 216) {
      int id = (wb - 72) * 256 + t;
      int lane = id & 63;
      int nb = (id >> 6) & 7;
      int kstep = id >> 9;
      int chunk = kstep >> 2, ks4 = kstep & 3;
      int g = chunk / 9, kk = chunk % 9;
      int o = nb * 16 + (lane & 15);
      int cb = g * 128 + ks4 * 32 + ((lane >> 4) * 8);
      s8v r;
#pragma unroll
      for (int j = 0; j < 8; ++j) r[j] = (short)f2bf(w_d[((size_t)o * 256 + cb + j) * 9 + kk]);
      *(s8v*)&wt_d[(size_t)id * 8] = r;
    } else {
      int id = (wb - 216) * 256 + t;
      int lane = id & 63;
      int nb = (id >> 6) & 7;
      int kstep = id >> 9;
      int ks2 = kstep & 1, tap = (kstep >> 1) % 9, cc = kstep / 18;
      int o = nb * 16 + (lane & 15);
      int cb = cc * 64 + ks2 * 32 + ((lane >> 4) * 8);
      s8v r;
#pragma unroll
      for (int j = 0; j < 8; ++j) r[j] = (short)f2bf(w_2[((size_t)o * 128 + cb + j) * 9 + tap]);
      *(s8v*)&wt_2[(size_t)id * 8] = r;
    }
  } else {  // stats zero
    stats[t] = 0.f;
    stats[256 + t] = 0.f;
  }
}

// ---------------- offset conv: waves = og(4) x kh(2), M=32 (unchanged) ----------------
__global__ __launch_bounds__(512, 3) void k_offconv(const unsigned short* __restrict__ xb,
                                                    const unsigned short* __restrict__ wt,
                                                    const float* __restrict__ bias,
                                                    float* __restrict__ off) {
  __shared__ char Xs[102 * 512];
  __shared__ float redx[2048];
  int bid = blockIdx.x;
  int id8 = (bid & 7) * 64 + (bid >> 3);
  int w0 = (id8 & 1) * 32;
  int h = (id8 >> 1) & 63;
  int b = id8 >> 7;
  int t = threadIdx.x;
  int l = t & 63, wv = t >> 6;
  int og = wv & 3, kh = wv >> 2;
  f4v zero = {0.f, 0.f, 0.f, 0.f};
  f4v acc[2] = {zero, zero};

  for (int id = t; id < 3264; id += 512) {
    int tr = id >> 5, oq8 = id & 31;
    int ky = tr / 34, col = tr % 34;
    int hh = h + ky - 1, ww = w0 + col - 1;
    s8v val = {0, 0, 0, 0, 0, 0, 0, 0};
    if ((unsigned)hh < 64u && (unsigned)ww < 64u)
      val = *(const s8v*)&xb[(((size_t)(b * 64 + hh)) * 64 + ww) * 256 + oq8 * 8];
    int byte = (tr * 512 + oq8 * 16) ^ ((tr & 7) << 4);
    *(s8v*)(Xs + byte) = val;
  }
  __syncthreads();
  int khi = l >> 4, lo = l & 15;
#pragma unroll
  for (int tap = 0; tap < 9; ++tap) {
    int ky = tap / 3, kx = tap % 3;
#pragma unroll
    for (int s = 0; s < 4; ++s) {
      int cc = kh * 2 + (s >> 1);
      int ks2 = s & 1;
      int kstep = cc * 18 + tap * 2 + ks2;
      int chb = cc * 128 + ks2 * 64 + khi * 16;
      s8v bfr = *(const s8v*)&wt[((size_t)(kstep * 4 + og) * 64 + l) * 8];
#pragma unroll
      for (int m = 0; m < 2; ++m) {
        int tr = ky * 34 + m * 16 + lo + kx;
        int rbyte = (tr * 512 + chb) ^ ((tr & 7) << 4);
        s8v a = *(const s8v*)(Xs + rbyte);
        acc[m] = __builtin_amdgcn_mfma_f32_16x16x32_bf16(a, bfr, acc[m], 0, 0, 0);
      }
    }
  }
  if (kh == 1) {
#pragma unroll
    for (int m = 0; m < 2; ++m)
#pragma unroll
      for (int j = 0; j < 4; ++j) redx[((og * 64 + l) * 2 + m) * 4 + j] = acc[m][j];
  }
  __syncthreads();
  if (kh == 0) {
    int o = og * 16 + lo;
    int pixb = (b * 64 + h) * 64 + w0;
    if (o < 54) {
      float bi = bias[o];
#pragma unroll
      for (int m = 0; m < 2; ++m)
#pragma unroll
        for (int j = 0; j < 4; ++j) {
          int px = pixb + m * 16 + khi * 4 + j;
          float vv = acc[m][j] + redx[((og * 64 + l) * 2 + m) * 4 + j] + bi;
          if (o >= 36) vv = 1.f / (1.f + __expf(-vv));
          off[(size_t)px * 54 + o] = vv;
        }
    }
  }
}

// ---------------- deform sample + dconv: 3-deep pipeline, triple-buffered LDS (unchanged) ----------------
#define DC_ISSUE(c, V, Q)                                   \
  do {                                                      \
    const unsigned* ip_ = sidx[(c)][px];                    \
    const float* qp_ = swt[(c)][px];                        \
    Q##0 = qp_[0]; Q##1 = qp_[1]; Q##2 = qp_[2]; Q##3 = qp_[3]; \
    V##0 = *(const s8v*)&xb[ip_[0] + chof];                 \
    V##1 = *(const s8v*)&xb[ip_[1] + chof];                 \
    V##2 = *(const s8v*)&xb[ip_[2] + chof];                 \
    V##3 = *(const s8v*)&xb[ip_[3] + chof];                 \
  } while (0)

#define DC_COMMIT(BUF, V, Q)                                            \
  do {                                                                  \
    unsigned rr_[4];                                                    \
    _Pragma("unroll") for (int jp_ = 0; jp_ < 4; ++jp_) {               \
      unsigned w0_ = ((const unsigned*)&V##0)[jp_];                     \
      unsigned w1_ = ((const unsigned*)&V##1)[jp_];                     \
      unsigned w2_ = ((const unsigned*)&V##2)[jp_];                     \
      unsigned w3_ = ((const unsigned*)&V##3)[jp_];                     \
      float e_ = Q##0 * __uint_as_float(w0_ << 16) + Q##1 * __uint_as_float(w1_ << 16) + \
                 Q##2 * __uint_as_float(w2_ << 16) + Q##3 * __uint_as_float(w3_ << 16);  \
      float o_ = Q##0 * __uint_as_float(w0_ & 0xffff0000u) + Q##1 * __uint_as_float(w1_ & 0xffff0000u) + \
                 Q##2 * __uint_as_float(w2_ & 0xffff0000u) + Q##3 * __uint_as_float(w3_ & 0xffff0000u);  \
      unsigned p_;                                                      \
      asm("v_cvt_pk_bf16_f32 %0, %1, %2" : "=v"(p_) : "v"(e_), "v"(o_)); \
      rr_[jp_] = p_;                                                    \
    }                                                                   \
    *(int4*)(&At[BUF][0] + wbyte) = *(int4*)rr_;                        \
  } while (0)

#define LDS_BARRIER()                                        \
  do {                                                       \
    asm volatile("s_waitcnt lgkmcnt(0)" ::: "memory");       \
    __builtin_amdgcn_s_barrier();                            \
  } while (0)

#define DC_MFMA(C, BUF)                                                 \
  do {                                                                  \
    __builtin_amdgcn_s_setprio(1);                                      \
    _Pragma("unroll") for (int ks4_ = 0; ks4_ < 4; ++ks4_) {            \
      int kstep_ = (C) * 4 + ks4_;                                      \
      s8v bfr_ = *(const s8v*)&wt[((size_t)(kstep_ * 8 + og) * 64 + l) * 8]; \
      int chb_ = ks4_ * 64 + khi * 16;                                  \
      _Pragma("unroll") for (int m_ = 0; m_ < 2; ++m_) {                \
        int trA_ = m_ * 16 + lo;                                        \
        int rbyte_ = (trA_ * 256 + chb_) ^ ((trA_ & 7) << 4);           \
        s8v a_ = *(const s8v*)(&At[BUF][0] + rbyte_);                   \
        acc[m_] = __builtin_amdgcn_mfma_f32_16x16x32_bf16(a_, bfr_, acc[m_], 0, 0, 0); \
      }                                                                 \
    }                                                                   \
    __builtin_amdgcn_s_setprio(0);                                      \
  } while (0)

#define DC_PHASE(C, BUF, VI, QI, VC, QC, BUFC)               \
  do {                                                       \
    if ((C) < 15) DC_ISSUE((C) + 3, VI, QI);                 \
    DC_MFMA(C, BUF);                                         \
    if ((C) < 17) DC_COMMIT(BUFC, VC, QC);                   \
    LDS_BARRIER();                                           \
  } while (0)

__global__ __launch_bounds__(512, 4) void k_dconv(const unsigned short* __restrict__ xb,
                                                  const float* __restrict__ off,
                                                  const unsigned short* __restrict__ wt,
                                                  float* __restrict__ y1p,
                                                  float* __restrict__ st1, float* __restrict__ st2) {
  __shared__ unsigned int sidx[18][32][4];
  __shared__ float swt[18][32][4];
  __shared__ char At[3][8192];
  int t = threadIdx.x;
  int l = t & 63, og = t >> 6;
  int bid = blockIdx.x;
  int id8 = (bid & 7) * 64 + (bid >> 3);
  int pixb = id8 * 32;
  int b = pixb >> 12, h = (pixb >> 6) & 63, w0 = pixb & 63;

  for (int id = t; id < 576; id += 512) {
    int chunk = id >> 5, ppx = id & 31;
    int g = chunk / 9, kk = chunk % 9;
    const float* op = off + (size_t)(pixb + ppx) * 54;
    float dy = op[(g * 9 + kk) * 2];
    float dx = op[(g * 9 + kk) * 2 + 1];
    float msk = op[36 + g * 9 + kk];
    float py = dy + (float)(h + kk / 3 - 1);
    float pxf = dx + (float)(w0 + ppx + kk % 3 - 1);
    float y0f = floorf(py), x0f = floorf(pxf);
    float ly = py - y0f, lx = pxf - x0f;
    int y0 = (int)y0f, x0 = (int)x0f;
    int y1 = y0 + 1, x1 = x0 + 1;
    float oky0 = (y0 >= 0 && y0 < 64) ? 1.f : 0.f;
    float oky1 = (y1 >= 0 && y1 < 64) ? 1.f : 0.f;
    float okx0 = (x0 >= 0 && x0 < 64) ? 1.f : 0.f;
    float okx1 = (x1 >= 0 && x1 < 64) ? 1.f : 0.f;
    int y0c = min(max(y0, 0), 63), y1c = min(max(y1, 0), 63);
    int x0c = min(max(x0, 0), 63), x1c = min(max(x1, 0), 63);
    unsigned base = (unsigned)(b * 4096);
    unsigned gofs = (unsigned)(g * 128);
    sidx[chunk][ppx][0] = (base + y0c * 64 + x0c) * 256u + gofs;
    sidx[chunk][ppx][1] = (base + y0c * 64 + x1c) * 256u + gofs;
    sidx[chunk][ppx][2] = (base + y1c * 64 + x0c) * 256u + gofs;
    sidx[chunk][ppx][3] = (base + y1c * 64 + x1c) * 256u + gofs;
    swt[chunk][ppx][0] = (1.f - ly) * (1.f - lx) * oky0 * okx0 * msk;
    swt[chunk][ppx][1] = (1.f - ly) * lx * oky0 * okx1 * msk;
    swt[chunk][ppx][2] = ly * (1.f - lx) * oky1 * okx0 * msk;
    swt[chunk][ppx][3] = ly * lx * oky1 * okx1 * msk;
  }
  __syncthreads();

  int px = t >> 4, oq = t & 15;
  unsigned chof = oq * 8u;
  int wbyte = (px * 256 + oq * 16) ^ ((px & 7) << 4);
  int khi = l >> 4, lo = l & 15;

  s8v va0, va1, va2, va3, vb0, vb1, vb2, vb3, vc0, vc1, vc2, vc3;
  float qa0, qa1, qa2, qa3, qb0, qb1, qb2, qb3, qc0, qc1, qc2, qc3;

  DC_ISSUE(0, va, qa);
  DC_ISSUE(1, vb, qb);
  DC_ISSUE(2, vc, qc);
  DC_COMMIT(0, va, qa);
  LDS_BARRIER();

  f4v zero = {0.f, 0.f, 0.f, 0.f};
  f4v acc[2] = {zero, zero};

  for (int cb = 0; cb < 6; ++cb) {
    int c0 = cb * 3;
    DC_PHASE(c0 + 0, 0, va, qa, vb, qb, 1);
    DC_PHASE(c0 + 1, 1, vb, qb, vc, qc, 2);
    DC_PHASE(c0 + 2, 2, vc, qc, va, qa, 0);
  }

  int o = og * 16 + lo;
  float s1v = 0.f, s2v = 0.f;
#pragma unroll
  for (int m = 0; m < 2; ++m)
#pragma unroll
    for (int j = 0; j < 4; ++j) {
      float vv = acc[m][j];
      y1p[(size_t)(pixb + m * 16 + khi * 4 + j) * 128 + o] = vv;
      s1v += vv; s2v += vv * vv;
    }
  float* red = &swt[0][0][0];
  red[khi * 128 + o] = s1v;
  red[512 + khi * 128 + o] = s2v;
  __syncthreads();
  if (t < 128) {
    float a1 = 0.f, a2 = 0.f;
#pragma unroll
    for (int rr = 0; rr < 4; ++rr) { a1 += red[rr * 128 + t]; a2 += red[512 + rr * 128 + t]; }
    atomicAdd(&st1[t], a1);
    atomicAdd(&st2[t], a2);
  }
}

// ---------------- conv2: bn1+relu fused into staging, bf16 output, stats-from-rounded ----------------
__global__ __launch_bounds__(512, 3) void k_conv2(const float* __restrict__ y1p,
                                                  const unsigned short* __restrict__ wt,
                                                  const float* __restrict__ s1, const float* __restrict__ s2,
                                                  const float* __restrict__ g1, const float* __restrict__ b1,
                                                  unsigned short* __restrict__ y2b,
                                                  float* __restrict__ st1, float* __restrict__ st2) {
  __shared__ char Bs[102 * 256];
  __shared__ float sc[128], sh[128];
  int bid = blockIdx.x;
  int id8 = (bid & 7) * 64 + (bid >> 3);
  int w0 = (id8 & 1) * 32;
  int h = (id8 >> 1) & 63;
  int b = id8 >> 7;
  int t = threadIdx.x;
  int l = t & 63, og = t >> 6;
  if (t < 128) {
    float m = s1[t] * (1.f / 16384.f);
    float var = s2[t] * (1.f / 16384.f) - m * m;
    float s = g1[t] * rsqrtf(var + EPSBN);
    sc[t] = s;
    sh[t] = b1[t] - m * s;
  }
  __syncthreads();
  f4v zero = {0.f, 0.f, 0.f, 0.f};
  f4v acc[2] = {zero, zero};

  for (int id = t; id < 1632; id += 512) {
    int tr = id >> 4, oq = id & 15;
    int ky = tr / 34, col = tr % 34;
    int hh = h + ky - 1, ww = w0 + col - 1;
    s8v val = {0, 0, 0, 0, 0, 0, 0, 0};
    if ((unsigned)hh < 64u && (unsigned)ww < 64u) {
      const float* src = y1p + (((size_t)(b * 64 + hh)) * 64 + ww) * 128 + oq * 8;
      float4 u = *(const float4*)src;
      float4 w4 = *(const float4*)(src + 4);
      int c = oq * 8;
      val[0] = (short)f2bf(fmaxf(0.f, u.x * sc[c + 0] + sh[c + 0]));
      val[1] = (short)f2bf(fmaxf(0.f, u.y * sc[c + 1] + sh[c + 1]));
      val[2] = (short)f2bf(fmaxf(0.f, u.z * sc[c + 2] + sh[c + 2]));
      val[3] = (short)f2bf(fmaxf(0.f, u.w * sc[c + 3] + sh[c + 3]));
      val[4] = (short)f2bf(fmaxf(0.f, w4.x * sc[c + 4] + sh[c + 4]));
      val[5] = (short)f2bf(fmaxf(0.f, w4.y * sc[c + 5] + sh[c + 5]));
      val[6] = (short)f2bf(fmaxf(0.f, w4.z * sc[c + 6] + sh[c + 6]));
      val[7] = (short)f2bf(fmaxf(0.f, w4.w * sc[c + 7] + sh[c + 7]));
    }
    int byte = (tr * 256 + oq * 16) ^ ((tr & 7) << 4);
    *(s8v*)(Bs + byte) = val;
  }
  __syncthreads();
  int khi = l >> 4, lo = l & 15;
#pragma unroll
  for (int tap = 0; tap < 9; ++tap) {
    int ky = tap / 3, kx = tap % 3;
#pragma unroll
    for (int ks4 = 0; ks4 < 4; ++ks4) {
      int kstep = ((ks4 >> 1) * 9 + tap) * 2 + (ks4 & 1);
      s8v bfr = *(const s8v*)&wt[((size_t)(kstep * 8 + og) * 64 + l) * 8];
      int chb = ks4 * 64 + khi * 16;
#pragma unroll
      for (int m = 0; m < 2; ++m) {
        int tr = ky * 34 + m * 16 + lo + kx;
        int rbyte = (tr * 256 + chb) ^ ((tr & 7) << 4);
        s8v a = *(const s8v*)(Bs + rbyte);
        acc[m] = __builtin_amdgcn_mfma_f32_16x16x32_bf16(a, bfr, acc[m], 0, 0, 0);
      }
    }
  }
  __syncthreads();
  int pixb = (b * 64 + h) * 64 + w0;
  int o = og * 16 + lo;
  float s1v = 0.f, s2v = 0.f;
#pragma unroll
  for (int m = 0; m < 2; ++m)
#pragma unroll
    for (int j = 0; j < 4; ++j) {
      unsigned short us = f2bf(acc[m][j]);
      y2b[(size_t)(pixb + m * 16 + khi * 4 + j) * 128 + o] = us;
      float vr = bf2f(us);
      s1v += vr; s2v += vr * vr;
    }
  float* red = (float*)Bs;
  red[khi * 128 + o] = s1v;
  red[512 + khi * 128 + o] = s2v;
  __syncthreads();
  if (t < 128) {
    float a1 = 0.f, a2 = 0.f;
#pragma unroll
    for (int rr = 0; rr < 4; ++rr) { a1 += red[rr * 128 + t]; a2 += red[512 + rr * 128 + t]; }
    atomicAdd(&st1[t], a1);
    atomicAdd(&st2[t], a2);
  }
}

// ---------------- bn2 + relu + NHWC bf16 -> NCHW f32 (LDS-transposed) ----------------
__global__ __launch_bounds__(256) void k_bnrelu2(const unsigned short* __restrict__ yb,
                                                 const float* __restrict__ s1, const float* __restrict__ s2,
                                                 const float* __restrict__ g, const float* __restrict__ bb,
                                                 float* __restrict__ out) {
  __shared__ float sc[128], sh[128];
  __shared__ float buf[64 * 129];
  int t = threadIdx.x;
  if (t < 128) {
    float m = s1[t] * (1.f / 16384.f);
    float var = s2[t] * (1.f / 16384.f) - m * m;
    float s = g[t] * rsqrtf(var + EPSBN);
    sc[t] = s;
    sh[t] = bb[t] - m * s;
  }
  int bh = blockIdx.x;
  int b = bh >> 6, h = bh & 63;
  const unsigned short* src = yb + (size_t)bh * 8192;
  for (int i = t; i < 1024; i += 256) {
    s8v v = *(const s8v*)&src[i * 8];
    int w = i >> 4;
    int o = (i & 15) * 8;
    float* d = &buf[w * 129 + o];
#pragma unroll
    for (int j = 0; j < 8; ++j) d[j] = bf2f((unsigned short)v[j]);
  }
  __syncthreads();
  for (int id = t; id < 8192; id += 256) {
    int o = id >> 6, w = id & 63;
    float v = buf[w * 129 + o];
    v = fmaxf(0.f, v * sc[o] + sh[o]);
    out[(((size_t)b * 128 + o) * 64 + h) * 64 + w] = v;
  }
}

extern "C" void kernel_launch(void* const* d_in, const int* in_sizes, int n_in,
                              void* d_out, int out_size, void* d_ws, size_t ws_size,
                              hipStream_t stream) {
  const float* in_v = (const float*)d_in[0];
  const float* in_i = (const float*)d_in[1];
  const float* off_w = (const float*)d_in[2];
  const float* off_b = (const float*)d_in[3];
  const float* dconv_w = (const float*)d_in[4];
  const float* bn1_g = (const float*)d_in[5];
  const float* bn1_b = (const float*)d_in[6];
  const float* conv2_w = (const float*)d_in[7];
  const float* bn2_g = (const float*)d_in[8];
  const float* bn2_b = (const float*)d_in[9];
  float* out = (float*)d_out;

  char* w = (char*)d_ws;
  unsigned short* xb = (unsigned short*)w;      w += (size_t)16384 * 256 * 2;  // 8 MB
  float* off_nhwc = (float*)w;                  w += (size_t)16384 * 54 * 4;   // 3.4 MB
  unsigned short* wtf_off = (unsigned short*)w; w += (size_t)18432 * 8 * 2;    // 288 KB
  unsigned short* wtf_d = (unsigned short*)w;   w += (size_t)36864 * 8 * 2;    // 576 KB
  unsigned short* wtf_2 = (unsigned short*)w;   w += (size_t)18432 * 8 * 2;    // 288 KB
  float* y1p = (float*)w;                       w += (size_t)16384 * 128 * 4;  // 8 MB
  unsigned short* y2b = (unsigned short*)w;     w += (size_t)16384 * 128 * 2;  // 4 MB
  float* stats = (float*)w;                     w += 512 * 4;

  k_prep<<<2337, 256, 0, stream>>>(in_v, in_i, off_w, dconv_w, conv2_w, xb, wtf_off, wtf_d, wtf_2, stats);
  k_offconv<<<512, 512, 0, stream>>>(xb, wtf_off, off_b, off_nhwc);
  k_dconv<<<512, 512, 0, stream>>>(xb, off_nhwc, wtf_d, y1p, stats, stats + 128);
  k_conv2<<<512, 512, 0, stream>>>(y1p, wtf_2, stats, stats + 128, bn1_g, bn1_b, y2b, stats + 256, stats + 384);
  k_bnrelu2<<<256, 256, 0, stream>>>(y2b, stats + 256, stats + 384, bn2_g, bn2_b, out);
}